// Round 1
// baseline (1671.228 us; speedup 1.0000x reference)
//
#include <hip/hip_runtime.h>

// Scaled dot product attention, [B=4,H=16,S=2048,D=64] fp32, returns (output, attn).
// d_out layout: output [4*16*2048*64] floats, then attn [4*16*2048*2048] floats.
//
// Strategy: per workgroup (256 thr = 4 waves) handle one head x 64 Q-rows.
// Wave w owns 16 Q-rows. Two passes over K:
//   pass 1: scores via mfma_f32_16x16x32_bf16, accumulate l = sum(exp(s)) per row
//   pass 2: recompute scores, p = exp(s)/l, write attn, accumulate PV via MFMA
// K/V tiles (32 keys) staged in LDS as bf16 (V transposed for B-fragment b128 reads).
// P round-trips through per-wave LDS to convert C/D layout -> A layout (m120 pattern).

#define S 2048
#define D 64
#define BH 64
#define TEMP_INV 0.125f

using short8  = __attribute__((ext_vector_type(8))) short;
using floatx4 = __attribute__((ext_vector_type(4))) float;

static __device__ __forceinline__ short bf(float f) {
  union { float f; unsigned u; } c; c.f = f;
  unsigned r = c.u + 0x7fffu + ((c.u >> 16) & 1u);  // RNE
  return (short)(r >> 16);
}

constexpr int KS  = 72;  // K tile row stride, bf16 elems (32 rows x [64 d + 8 pad])
constexpr int VTS = 40;  // V^T tile row stride, bf16 elems (64 d x [32 keys + 8 pad])
constexpr int PS  = 36;  // P tile row stride, fp32 (16 rows x [32 keys + 4 pad])

__global__ __launch_bounds__(256)
void sdpa_kernel(const float* __restrict__ q, const float* __restrict__ k,
                 const float* __restrict__ v, float* __restrict__ out) {
  __shared__ __align__(16) short Kt[32 * KS];
  __shared__ __align__(16) short VT[64 * VTS];
  __shared__ __align__(16) float Pl[4][16 * PS];

  // XCD swizzle: all 32 blocks of a head share blockIdx%8 -> same XCD L2.
  const int g    = blockIdx.x;
  const int xcd  = g & 7;
  const int s    = g >> 3;            // 0..255
  const int head = xcd + 8 * (s >> 5);
  const int qt   = s & 31;            // q tile within head, 64 rows each

  const int tid  = threadIdx.x;
  const int wave = tid >> 6;
  const int lane = tid & 63;
  const int quad = lane >> 4;
  const int l16  = lane & 15;

  const size_t headOff = (size_t)head * S * D;
  const int    qrow0   = qt * 64 + wave * 16;   // this wave's first q row

  // Q fragments (held in registers for the whole kernel). A-layout:
  // A[m=lane&15][kd=quad*8+j]; qa covers kd 0..31, qb covers kd 32..63.
  const float* qr = q + headOff + (size_t)(qrow0 + l16) * D;
  short8 qa, qb;
#pragma unroll
  for (int j = 0; j < 8; ++j) {
    qa[j] = bf(qr[quad * 8 + j] * TEMP_INV);
    qb[j] = bf(qr[32 + quad * 8 + j] * TEMP_INV);
  }

  const float* kg = k + headOff;
  const float* vg = v + headOff;

  // ---------------- pass 1: row sums of exp(scores) ----------------
  float l[4] = {0.f, 0.f, 0.f, 0.f};
  for (int jt = 0; jt < 64; ++jt) {
    __syncthreads();
    {  // stage K tile: 32 keys x 64 d fp32 -> bf16 LDS (row-major, padded)
      const float4* src = (const float4*)(kg + (size_t)jt * 32 * D);
#pragma unroll
      for (int i = tid; i < 512; i += 256) {
        float4 f = src[i];
        int key = i >> 4, d4 = (i & 15) * 4;
        short4 sv; sv.x = bf(f.x); sv.y = bf(f.y); sv.z = bf(f.z); sv.w = bf(f.w);
        *(short4*)&Kt[key * KS + d4] = sv;
      }
    }
    __syncthreads();
#pragma unroll
    for (int h = 0; h < 2; ++h) {
      // B-layout: B[kd=quad*8+j][n=key=lane&15] = K[key][kd]
      short8 b0 = *(const short8*)&Kt[(h * 16 + l16) * KS + quad * 8];
      short8 b1 = *(const short8*)&Kt[(h * 16 + l16) * KS + 32 + quad * 8];
      floatx4 acc = {0.f, 0.f, 0.f, 0.f};
      acc = __builtin_amdgcn_mfma_f32_16x16x32_bf16(qa, b0, acc, 0, 0, 0);
      acc = __builtin_amdgcn_mfma_f32_16x16x32_bf16(qb, b1, acc, 0, 0, 0);
      // C/D layout: row = quad*4 + r, col(key) = lane&15
#pragma unroll
      for (int r = 0; r < 4; ++r) l[r] += __expf(acc[r]);
    }
  }
  // reduce across the 16 lanes of each quad (they share rows, cover all keys)
#pragma unroll
  for (int off = 1; off < 16; off <<= 1) {
#pragma unroll
    for (int r = 0; r < 4; ++r) l[r] += __shfl_xor(l[r], off);
  }
  float rcp[4];
#pragma unroll
  for (int r = 0; r < 4; ++r) rcp[r] = 1.0f / l[r];

  // ---------------- pass 2: attn write + PV ----------------
  floatx4 accO[4];
#pragma unroll
  for (int d0 = 0; d0 < 4; ++d0) accO[d0] = floatx4{0.f, 0.f, 0.f, 0.f};

  float* attn = out + (size_t)BH * S * D;  // attn section of d_out
  float* arow = attn + (size_t)head * S * S + (size_t)qrow0 * S;

  for (int jt = 0; jt < 64; ++jt) {
    __syncthreads();
    {  // stage K tile
      const float4* src = (const float4*)(kg + (size_t)jt * 32 * D);
#pragma unroll
      for (int i = tid; i < 512; i += 256) {
        float4 f = src[i];
        int key = i >> 4, d4 = (i & 15) * 4;
        short4 sv; sv.x = bf(f.x); sv.y = bf(f.y); sv.z = bf(f.z); sv.w = bf(f.w);
        *(short4*)&Kt[key * KS + d4] = sv;
      }
      // stage V tile transposed: VT[d][key]
      const float4* vsrc = (const float4*)(vg + (size_t)jt * 32 * D);
#pragma unroll
      for (int i = tid; i < 512; i += 256) {
        float4 f = vsrc[i];
        int key = i >> 4, d4 = (i & 15) * 4;
        VT[(d4 + 0) * VTS + key] = bf(f.x);
        VT[(d4 + 1) * VTS + key] = bf(f.y);
        VT[(d4 + 2) * VTS + key] = bf(f.z);
        VT[(d4 + 3) * VTS + key] = bf(f.w);
      }
    }
    __syncthreads();

    floatx4 sc[2];
#pragma unroll
    for (int h = 0; h < 2; ++h) {
      short8 b0 = *(const short8*)&Kt[(h * 16 + l16) * KS + quad * 8];
      short8 b1 = *(const short8*)&Kt[(h * 16 + l16) * KS + 32 + quad * 8];
      floatx4 acc = {0.f, 0.f, 0.f, 0.f};
      acc = __builtin_amdgcn_mfma_f32_16x16x32_bf16(qa, b0, acc, 0, 0, 0);
      acc = __builtin_amdgcn_mfma_f32_16x16x32_bf16(qb, b1, acc, 0, 0, 0);
      sc[h] = acc;
    }

    // normalized p; write attn (fp32) and P-LDS (per-wave, no barrier needed)
#pragma unroll
    for (int h = 0; h < 2; ++h) {
#pragma unroll
      for (int r = 0; r < 4; ++r) {
        float p = __expf(sc[h][r]) * rcp[r];
        arow[(size_t)(quad * 4 + r) * S + jt * 32 + h * 16 + l16] = p;
        Pl[wave][(quad * 4 + r) * PS + h * 16 + l16] = p;
      }
    }

    // read P back in A-layout: A[m=lane&15][key=quad*8+j], convert to bf16
    float4 pa = *(const float4*)&Pl[wave][l16 * PS + quad * 8];
    float4 pb = *(const float4*)&Pl[wave][l16 * PS + quad * 8 + 4];
    short8 pf;
    pf[0] = bf(pa.x); pf[1] = bf(pa.y); pf[2] = bf(pa.z); pf[3] = bf(pa.w);
    pf[4] = bf(pb.x); pf[5] = bf(pb.y); pf[6] = bf(pb.z); pf[7] = bf(pb.w);

    // PV: B[k=key=quad*8+j][n=d0*16+lane&15] = V[key][d] = VT[d][key]
#pragma unroll
    for (int d0 = 0; d0 < 4; ++d0) {
      short8 vf = *(const short8*)&VT[(d0 * 16 + l16) * VTS + quad * 8];
      accO[d0] = __builtin_amdgcn_mfma_f32_16x16x32_bf16(pf, vf, accO[d0], 0, 0, 0);
    }
  }

  // epilogue: out[row][d], C/D layout row=quad*4+r, col=d0*16+lane&15
  float* orow = out + headOff;
#pragma unroll
  for (int d0 = 0; d0 < 4; ++d0) {
#pragma unroll
    for (int r = 0; r < 4; ++r) {
      orow[(size_t)(qrow0 + quad * 4 + r) * D + d0 * 16 + l16] = accO[d0][r];
    }
  }
}

extern "C" void kernel_launch(void* const* d_in, const int* in_sizes, int n_in,
                              void* d_out, int out_size, void* d_ws, size_t ws_size,
                              hipStream_t stream) {
  const float* q = (const float*)d_in[0];
  const float* k = (const float*)d_in[1];
  const float* v = (const float*)d_in[2];
  float* out = (float*)d_out;
  sdpa_kernel<<<2048, 256, 0, stream>>>(q, k, v, out);
}